// Round 6
// baseline (929.200 us; speedup 1.0000x reference)
//
#include <hip/hip_runtime.h>
#include <hip/hip_bf16.h>

#define BB 4
#define TT 4096
#define DD 2048
#define BOTC 256

typedef __bf16 bf16;
typedef __attribute__((ext_vector_type(4))) __bf16 bf16x4;
typedef __attribute__((ext_vector_type(8))) __bf16 bf16x8;
typedef __attribute__((ext_vector_type(4))) float f32x4;

constexpr int BM = 128, BN = 128, BK = 64;

__device__ __forceinline__ void async16(const void* g, bf16* l) {
  __builtin_amdgcn_global_load_lds((const __attribute__((address_space(1))) void*)g,
                                   (__attribute__((address_space(3))) void*)l, 16, 0, 0);
}

#define SBAR asm volatile("s_barrier" ::: "memory")
#define WAIT_LGKM0 asm volatile("s_waitcnt lgkmcnt(0)" ::: "memory")
#define LGKM_HINT8 asm volatile("s_waitcnt lgkmcnt(8)" ::: "memory")
#define WAIT_VM4 asm volatile("s_waitcnt vmcnt(4)" ::: "memory")
#define WAIT_VM0 asm volatile("s_waitcnt vmcnt(0)" ::: "memory")

// ---------------- 128x128 tile GEMM (projection EPI=1, scores EPI=2) ----------------
// C[m,n] = sum_k A[m,k]*B[n,k]  (row-major, K contiguous; ldA/ldB row strides)
template <int EPI>
__global__ __launch_bounds__(256) void gemm_bt(
    const bf16* __restrict__ A, const bf16* __restrict__ Bm, void* __restrict__ Cout,
    const float* __restrict__ bias, int M, int N, int K, int ldA, int ldB,
    long sAb, long sBb, long sCb, float scale) {
  const int b = blockIdx.z;
  const int m0 = blockIdx.y * BM;
  const int n0 = blockIdx.x * BN;
  const int tid = threadIdx.x;
  const int lane = tid & 63;
  const int w = tid >> 6;
  const int wm = (w >> 1) * 64;
  const int wn = (w & 1) * 64;

  if (EPI == 2 && n0 > m0) return;  // fully masked: never written, never read

  __shared__ bf16 As[BM * BK];
  __shared__ bf16 Bs[BN * BK];

  f32x4 acc[4][4] = {};

  const bf16* Arow = A + (size_t)b * sAb + (size_t)m0 * ldA;
  const bf16* Brow = Bm + (size_t)b * sBb + (size_t)n0 * ldB;

  for (int k0 = 0; k0 < K; k0 += BK) {
#pragma unroll
    for (int j = 0; j < 4; ++j) {
      int c = j * 256 + tid;
      int row = c >> 3, kc = c & 7;
      int gk = kc ^ (row & 7);
      async16(Arow + (size_t)row * ldA + k0 + gk * 8, As + (size_t)c * 8);
      async16(Brow + (size_t)row * ldB + k0 + gk * 8, Bs + (size_t)c * 8);
    }
    __syncthreads();
    bf16x8 af[4][2], bfr[4][2];
#pragma unroll
    for (int mi = 0; mi < 4; ++mi)
#pragma unroll
      for (int kk = 0; kk < 2; ++kk) {
        int row = wm + mi * 16 + (lane & 15);
        int kc = kk * 4 + (lane >> 4);
        af[mi][kk] = *(const bf16x8*)(As + ((size_t)row * 8 + (kc ^ (row & 7))) * 8);
      }
#pragma unroll
    for (int ni = 0; ni < 4; ++ni)
#pragma unroll
      for (int kk = 0; kk < 2; ++kk) {
        int row = wn + ni * 16 + (lane & 15);
        int kc = kk * 4 + (lane >> 4);
        bfr[ni][kk] = *(const bf16x8*)(Bs + ((size_t)row * 8 + (kc ^ (row & 7))) * 8);
      }
#pragma unroll
    for (int kk = 0; kk < 2; ++kk)
#pragma unroll
      for (int mi = 0; mi < 4; ++mi)
#pragma unroll
        for (int ni = 0; ni < 4; ++ni)
          acc[mi][ni] = __builtin_amdgcn_mfma_f32_16x16x32_bf16(af[mi][kk], bfr[ni][kk], acc[mi][ni], 0, 0, 0);
    __syncthreads();
  }

  const int lcol = lane & 15;
  const int lrow = (lane >> 4) * 4;

  if (EPI == 1) {
    bf16* C = (bf16*)Cout + (size_t)b * sCb;
#pragma unroll
    for (int mi = 0; mi < 4; ++mi) {
      int rbase = m0 + wm + mi * 16 + lrow;
#pragma unroll
      for (int ni = 0; ni < 4; ++ni) {
        int col = n0 + wn + ni * 16 + lcol;
        float bv = bias[col];
#pragma unroll
        for (int r = 0; r < 4; ++r)
          C[(size_t)(rbase + r) * N + col] = (bf16)(acc[mi][ni][r] + bv);
      }
    }
  } else {
    bf16* C = (bf16*)Cout + (size_t)b * sCb;
#pragma unroll
    for (int mi = 0; mi < 4; ++mi) {
      int rbase = m0 + wm + mi * 16 + lrow;
#pragma unroll
      for (int ni = 0; ni < 4; ++ni) {
        int col = n0 + wn + ni * 16 + lcol;
#pragma unroll
        for (int r = 0; r < 4; ++r) {
          int i = rbase + r;
          float v = acc[mi][ni][r] * scale;
          if (col > i - 4) v = -65000.0f;
          C[(size_t)i * N + col] = (bf16)v;
        }
      }
    }
  }
}

// ---------------- 256x256 8-phase GEMM (final combined @ hdc, fp32 out) ----------------
// Stage one 128x64 bf16 half-tile (16 KB): 512 threads x 2 chunks of 16B.
// Global k-chunk pre-swizzled (gk = kc ^ (row&7)); LDS dest linear (gload_lds rule).
__device__ __forceinline__ void stage_half(const bf16* __restrict__ src, int ld,
                                           bf16* lds, int tid) {
#pragma unroll
  for (int j = 0; j < 2; ++j) {
    int c = j * 512 + tid;
    int row = c >> 3;
    int gk = (c & 7) ^ (row & 7);
    async16(src + (size_t)row * ld + gk * 8, lds + (size_t)c * 8);
  }
}

__device__ __forceinline__ bf16x8 fragrd(const bf16* base, int lr, int kc) {
  return *(const bf16x8*)(base + ((size_t)lr * 8 + (kc ^ (lr & 7))) * 8);
}

// B sub-quadrant for one qn (2 ni x 2 kk = 4 x ds_read_b128)
__device__ __forceinline__ void load_b2(const bf16* base, int wn, int fr, int fq,
                                        int qn, bf16x8 (&bq)[2][2]) {
#pragma unroll
  for (int ni = 0; ni < 2; ++ni)
#pragma unroll
    for (int kk = 0; kk < 2; ++kk)
      bq[ni][kk] = fragrd(base, (wn & 1) * 64 + (qn * 2 + ni) * 16 + fr, kk * 4 + fq);
}

// A half-quadrant for one qm (4 mi x 2 kk = 8 x ds_read_b128)
__device__ __forceinline__ void load_a4(const bf16* base, int qm, int fr, int fq,
                                        bf16x8 (&a)[4][2]) {
#pragma unroll
  for (int mi = 0; mi < 4; ++mi)
#pragma unroll
    for (int kk = 0; kk < 2; ++kk)
      a[mi][kk] = fragrd(base, qm * 64 + mi * 16 + fr, kk * 4 + fq);
}

__device__ __forceinline__ void mfma_quad(f32x4 (&acc)[8][4], const bf16x8 (&a)[4][2],
                                          const bf16x8 (&bq)[2][2], int qm, int qn) {
  __builtin_amdgcn_s_setprio(1);
#pragma unroll
  for (int kk = 0; kk < 2; ++kk)
#pragma unroll
    for (int mi = 0; mi < 4; ++mi)
#pragma unroll
      for (int ni = 0; ni < 2; ++ni)
        acc[qm * 4 + mi][qn * 2 + ni] = __builtin_amdgcn_mfma_f32_16x16x32_bf16(
            a[mi][kk], bq[ni][kk], acc[qm * 4 + mi][qn * 2 + ni], 0, 0, 0);
  __builtin_amdgcn_s_setprio(0);
}

// Schedule ledger (12/4/8/0 read distribution; audited R5):
//   reads: p0: A(b0,qm0)8+B(b0,qn0)4; p1: B(b0,qn1)4; p2: A(b0,qm1)8; p3: 0
//          p4-p7: same on b1.  Region last-reads: sB[x]: p1/p5; sA[x]: p2/p6.
//   stages (1/phase; 2 at p7, 0 at p6), iteration i:
//     p0: sB[1][0]<-B0(K2i+1)   (old last read p5 of i-1)
//     p1: sB[1][1]<-B1(K2i+1)   (same)
//     p2: sB[0][0]<-B0(K2i+2)   (old last read p1, >=1 barrier)
//     p3: sB[0][1]<-B1(K2i+2)   (same)
//     p4: sA[0][0]<-A0(K2i+2)   (old last read p2)
//     p5: sA[0][1]<-A1(K2i+2)   (same)
//     p6: none
//     p7: sA[1][0]<-A0(K2i+3), sA[1][1]<-A1(K2i+3)  (old last read p6)
//   waits: vmcnt(4) end of p3 (outstanding 12 -> lands p7(i-1).A(K2i+1) x2 +
//          p0,p1 B(K2i+1): everything p4 reads) and end of p7 (lands p2..p5 =
//          all buf0 K2i+2 needed at p0-next; leaves p7's A(K2i+3) in flight).
//   every write issues >=1 barrier after its region's last read.
// Grid fixed (8,16,4) = 512 blocks; swizzle compile-time masks only.
__global__ __launch_bounds__(512, 2) void gemm256(
    const bf16* __restrict__ A, const bf16* __restrict__ Bm, float* __restrict__ C,
    int N, int K, int ldA, int ldB, long sAb, long sBb, long sCb) {
  // T1: XCD-chunked swizzle (bijective, nwg=512 % 8 == 0): FETCH 557->197 MB (R4).
  const int h = blockIdx.x + 8 * (blockIdx.y + 16 * blockIdx.z);  // 0..511
  const int l = ((h & 7) << 6) + (h >> 3);
  const int bx = l & 7;
  const int lt = l >> 3;
  const int by = lt & 15;
  const int b = lt >> 4;
  const int m0 = by * 256;
  const int n0 = bx * 256;
  const int tid = threadIdx.x;
  const int lane = tid & 63;
  const int w = tid >> 6;
  const int wm = w >> 2;   // 0..1: A half / output row half
  const int wn = w & 3;    // 0..3: output col quarter
  const int fr = lane & 15;
  const int fq = lane >> 4;
  const int bh = wn >> 1;
  const int NKT = K >> 6;  // K-tiles of 64
  const int NI = K >> 7;   // iterations (2 K-tiles each)

  __shared__ bf16 sA[2][2][8192];  // [buf][half][128*64]
  __shared__ bf16 sB[2][2][8192];

  const bf16* Ab = A + (size_t)b * sAb + (size_t)m0 * ldA;
  const bf16* Bb = Bm + (size_t)b * sBb + (size_t)n0 * ldB;

  f32x4 acc[8][4] = {};
  bf16x8 a[4][2], bq0[2][2], bq1[2][2];

  // prologue: K0 {B0,B1,A0,A1} + K1 {A0,A1} = 6 half-tiles (12 loads)
  stage_half(Bb, ldB, &sB[0][0][0], tid);
  stage_half(Bb + (size_t)128 * ldB, ldB, &sB[0][1][0], tid);
  stage_half(Ab, ldA, &sA[0][0][0], tid);
  stage_half(Ab + (size_t)128 * ldA, ldA, &sA[0][1][0], tid);
  stage_half(Ab + 64, ldA, &sA[1][0][0], tid);
  stage_half(Ab + (size_t)128 * ldA + 64, ldA, &sA[1][1][0], tid);
  WAIT_VM4;  // K0's 4 half-tiles landed; A(K1) x2 in flight
  SBAR;

  for (int i = 0; i < NI; ++i) {
    const size_t k1 = (size_t)(2 * i + 1) * 64;  // <= K-64 always
    int t2 = 2 * i + 2; if (t2 > NKT - 1) t2 = NKT - 1;  // tail clamp: redundant
    int t3 = 2 * i + 3; if (t3 > NKT - 1) t3 = NKT - 1;  // re-loads keep vmcnt exact
    const size_t k2 = (size_t)t2 * 64, k3 = (size_t)t3 * 64;

    // p0: 12 reads; stage B0(K2i+1)
    load_a4(&sA[0][wm][0], 0, fr, fq, a);
    load_b2(&sB[0][bh][0], wn, fr, fq, 0, bq0);
    stage_half(Bb + k1, ldB, &sB[1][0][0], tid);
    LGKM_HINT8;
    SBAR; WAIT_LGKM0; __builtin_amdgcn_sched_barrier(0);
    mfma_quad(acc, a, bq0, 0, 0);
    SBAR;
    // p1: 4 reads; stage B1(K2i+1)
    load_b2(&sB[0][bh][0], wn, fr, fq, 1, bq1);
    stage_half(Bb + (size_t)128 * ldB + k1, ldB, &sB[1][1][0], tid);
    SBAR; WAIT_LGKM0; __builtin_amdgcn_sched_barrier(0);
    mfma_quad(acc, a, bq1, 0, 1);
    SBAR;
    // p2: 8 reads; stage B0(K2i+2)
    load_a4(&sA[0][wm][0], 1, fr, fq, a);
    stage_half(Bb + k2, ldB, &sB[0][0][0], tid);
    SBAR; WAIT_LGKM0; __builtin_amdgcn_sched_barrier(0);
    mfma_quad(acc, a, bq0, 1, 0);
    SBAR;
    // p3: 0 reads; stage B1(K2i+2); vmcnt(4)
    stage_half(Bb + (size_t)128 * ldB + k2, ldB, &sB[0][1][0], tid);
    SBAR;
    mfma_quad(acc, a, bq1, 1, 1);
    WAIT_VM4;  // K2i+1 (A from p7 of i-1, B from p0/p1) fully in LDS
    SBAR;
    // p4: 12 reads; stage A0(K2i+2)
    load_a4(&sA[1][wm][0], 0, fr, fq, a);
    load_b2(&sB[1][bh][0], wn, fr, fq, 0, bq0);
    stage_half(Ab + k2, ldA, &sA[0][0][0], tid);
    LGKM_HINT8;
    SBAR; WAIT_LGKM0; __builtin_amdgcn_sched_barrier(0);
    mfma_quad(acc, a, bq0, 0, 0);
    SBAR;
    // p5: 4 reads; stage A1(K2i+2)
    load_b2(&sB[1][bh][0], wn, fr, fq, 1, bq1);
    stage_half(Ab + (size_t)128 * ldA + k2, ldA, &sA[0][1][0], tid);
    SBAR; WAIT_LGKM0; __builtin_amdgcn_sched_barrier(0);
    mfma_quad(acc, a, bq1, 0, 1);
    SBAR;
    // p6: 8 reads; no stage
    load_a4(&sA[1][wm][0], 1, fr, fq, a);
    SBAR; WAIT_LGKM0; __builtin_amdgcn_sched_barrier(0);
    mfma_quad(acc, a, bq0, 1, 0);
    SBAR;
    // p7: 0 reads; stages A0(K2i+3), A1(K2i+3); vmcnt(4)
    stage_half(Ab + k3, ldA, &sA[1][0][0], tid);
    stage_half(Ab + (size_t)128 * ldA + k3, ldA, &sA[1][1][0], tid);
    SBAR;
    mfma_quad(acc, a, bq1, 1, 1);
    WAIT_VM4;  // all buf0 K2i+2 landed; A(K2i+3) in flight
    SBAR;
  }

  WAIT_VM0;  // drain tail re-loads before epilogue

  float* Cb = C + (size_t)b * sCb;
  const int lrow = fq * 4;
#pragma unroll
  for (int mi = 0; mi < 8; ++mi) {
    int rbase = m0 + wm * 128 + mi * 16 + lrow;
#pragma unroll
    for (int ni = 0; ni < 4; ++ni) {
      int col = n0 + wn * 64 + ni * 16 + fr;
#pragma unroll
      for (int r = 0; r < 4; ++r)
        Cb[(size_t)(rbase + r) * N + col] = acc[mi][ni][r];
    }
  }
}

// fp32 [B,T,D] -> bf16 [B,T,D] and bf16 transposed [B,D,T], 64x64 tiles, wide stores
__global__ __launch_bounds__(256) void conv_transpose(
    const float* __restrict__ hdc, bf16* __restrict__ hb, bf16* __restrict__ hT) {
  __shared__ float tile[64][65];
  int b = blockIdx.z;
  int d0 = blockIdx.x * 64, t0 = blockIdx.y * 64;
  int tid = threadIdx.x;
  const float* src = hdc + (size_t)b * TT * DD;
  bf16* dstb = hb + (size_t)b * TT * DD;
  bf16* dstT = hT + (size_t)b * DD * TT;
  int c4 = tid & 15, r0 = tid >> 4;
#pragma unroll
  for (int rr = 0; rr < 4; ++rr) {
    int r = rr * 16 + r0;
    float4 v = *(const float4*)(src + (size_t)(t0 + r) * DD + d0 + c4 * 4);
    tile[r][c4 * 4 + 0] = v.x;
    tile[r][c4 * 4 + 1] = v.y;
    tile[r][c4 * 4 + 2] = v.z;
    tile[r][c4 * 4 + 3] = v.w;
    bf16x4 o;
    o[0] = (bf16)v.x; o[1] = (bf16)v.y; o[2] = (bf16)v.z; o[3] = (bf16)v.w;
    *(bf16x4*)(dstb + (size_t)(t0 + r) * DD + d0 + c4 * 4) = o;
  }
  __syncthreads();
  int tc = tid & 7, dr0 = tid >> 3;
#pragma unroll
  for (int rr = 0; rr < 2; ++rr) {
    int dr = rr * 32 + dr0;
    bf16x8 o;
#pragma unroll
    for (int e = 0; e < 8; ++e) o[e] = (bf16)tile[tc * 8 + e][dr];
    *(bf16x8*)(dstT + (size_t)(d0 + dr) * TT + t0 + tc * 8) = o;
  }
}

// Wq,Wk fp32 [256,2048] -> stacked bf16 [512,2048]; bq,bk -> bqk fp32[512]
__global__ __launch_bounds__(256) void conv_w(
    const float* __restrict__ Wq, const float* __restrict__ Wk,
    const float* __restrict__ bq, const float* __restrict__ bk,
    bf16* __restrict__ Wqkb, float* __restrict__ bqk) {
  int i = blockIdx.x * 256 + threadIdx.x;
  float4 q = *(const float4*)(Wq + (size_t)i * 4);
  float4 k = *(const float4*)(Wk + (size_t)i * 4);
  bf16x4 qo, ko;
  qo[0] = (bf16)q.x; qo[1] = (bf16)q.y; qo[2] = (bf16)q.z; qo[3] = (bf16)q.w;
  ko[0] = (bf16)k.x; ko[1] = (bf16)k.y; ko[2] = (bf16)k.z; ko[3] = (bf16)k.w;
  *(bf16x4*)(Wqkb + (size_t)i * 4) = qo;
  *(bf16x4*)(Wqkb + (size_t)BOTC * DD + (size_t)i * 4) = ko;
  if (blockIdx.x == 0) {
    bqk[threadIdx.x] = bq[threadIdx.x];
    bqk[256 + threadIdx.x] = bk[threadIdx.x];
  }
}

// one block per row i: softmax over valid prefix (j < i-3) of S (bf16), then
// combined = 0.7*decay + 0.3*softmax written over the FULL row.
__global__ __launch_bounds__(256) void softmax_combine(
    bf16* __restrict__ S, const float* __restrict__ decay) {
  int b = blockIdx.y, i = blockIdx.x;
  bf16* srow = S + ((size_t)b * TT + i) * TT;
  const float* drow = decay + ((size_t)b * TT + i) * TT;
  int t = threadIdx.x;
  int lane = t & 63, w = t >> 6;
  const int valid = i - 3;
  const int nc = valid > 0 ? (valid + 7) >> 3 : 0;

  float p[2][8];
  float inv = 0.f, pc = 0.f;

  if (valid > 0) {
    float s[2][8];
#pragma unroll
    for (int u = 0; u < 2; ++u) {
      int c = u * 256 + t;
      if (c < nc) {
        bf16x8 sv = *(const bf16x8*)(srow + (size_t)c * 8);
#pragma unroll
        for (int e = 0; e < 8; ++e) {
          int j = c * 8 + e;
          s[u][e] = j < valid ? (float)sv[e] : -INFINITY;
        }
      } else {
#pragma unroll
        for (int e = 0; e < 8; ++e) s[u][e] = -INFINITY;
      }
    }
    float m = s[0][0];
#pragma unroll
    for (int u = 0; u < 2; ++u)
#pragma unroll
      for (int e = 0; e < 8; ++e) m = fmaxf(m, s[u][e]);
#pragma unroll
    for (int off = 32; off > 0; off >>= 1) m = fmaxf(m, __shfl_xor(m, off));
    __shared__ float redm[4], reds[4];
    if (lane == 0) redm[w] = m;
    __syncthreads();
    m = fmaxf(fmaxf(redm[0], redm[1]), fmaxf(redm[2], redm[3]));

    float sum = 0.f;
#pragma unroll
    for (int u = 0; u < 2; ++u)
#pragma unroll
      for (int e = 0; e < 8; ++e) {
        p[u][e] = __expf(s[u][e] - m);
        sum += p[u][e];
      }
#pragma unroll
    for (int off = 32; off > 0; off >>= 1) sum += __shfl_xor(sum, off);
    if (lane == 0) reds[w] = sum;
    __syncthreads();
    sum = reds[0] + reds[1] + reds[2] + reds[3];
    inv = 0.3f / sum;
  } else {
    pc = 0.3f / 4096.0f;
#pragma unroll
    for (int u = 0; u < 2; ++u)
#pragma unroll
      for (int e = 0; e < 8; ++e) p[u][e] = 0.f;
  }

#pragma unroll
  for (int u = 0; u < 2; ++u) {
    int c = u * 256 + t;
    const float4* d4 = (const float4*)(drow + (size_t)c * 8);
    float4 da = d4[0], db = d4[1];
    float pv[8];
#pragma unroll
    for (int e = 0; e < 8; ++e) pv[e] = p[u][e] * inv + pc;
    bf16x8 o;
    o[0] = (bf16)(0.7f * da.x + pv[0]);
    o[1] = (bf16)(0.7f * da.y + pv[1]);
    o[2] = (bf16)(0.7f * da.z + pv[2]);
    o[3] = (bf16)(0.7f * da.w + pv[3]);
    o[4] = (bf16)(0.7f * db.x + pv[4]);
    o[5] = (bf16)(0.7f * db.y + pv[5]);
    o[6] = (bf16)(0.7f * db.z + pv[6]);
    o[7] = (bf16)(0.7f * db.w + pv[7]);
    *(bf16x8*)(srow + (size_t)c * 8) = o;
  }
}

extern "C" void kernel_launch(void* const* d_in, const int* in_sizes, int n_in,
                              void* d_out, int out_size, void* d_ws, size_t ws_size,
                              hipStream_t stream) {
  (void)in_sizes; (void)n_in; (void)out_size; (void)ws_size;
  const float* hdc = (const float*)d_in[0];
  const float* decay = (const float*)d_in[1];
  const float* Wq = (const float*)d_in[2];
  const float* bq = (const float*)d_in[3];
  const float* Wk = (const float*)d_in[4];
  const float* bk = (const float*)d_in[5];
  float* out = (float*)d_out;

  char* ws = (char*)d_ws;
  bf16* hdc_b = (bf16*)ws; ws += (size_t)BB * TT * DD * 2;
  bf16* hdcT  = (bf16*)ws; ws += (size_t)BB * TT * DD * 2;
  bf16* Wqkb  = (bf16*)ws; ws += (size_t)2 * BOTC * DD * 2;
  float* bqk  = (float*)ws; ws += 2 * BOTC * 4;
  bf16* qk    = (bf16*)ws; ws += (size_t)BB * TT * 2 * BOTC * 2;
  bf16* S     = (bf16*)ws; ws += (size_t)BB * TT * TT * 2;

  // 1) hdc -> bf16 (+transposed); weights -> stacked bf16 + bias vec
  conv_transpose<<<dim3(DD / 64, TT / 64, BB), 256, 0, stream>>>(hdc, hdc_b, hdcT);
  conv_w<<<dim3(BOTC * DD / 1024), 256, 0, stream>>>(Wq, Wk, bq, bk, Wqkb, bqk);

  // 2) fused projection: [q|k] = hdc @ [Wq;Wk]^T + [bq;bk]   (M=B*T, N=512, K=2048)
  gemm_bt<1><<<dim3((2 * BOTC) / BN, (BB * TT) / BM, 1), 256, 0, stream>>>(
      hdc_b, Wqkb, qk, bqk, BB * TT, 2 * BOTC, DD, DD, DD, 0, 0, 0, 1.0f);

  // 3) scores = (q@k^T)/16 masked, bf16; masked tiles skipped entirely
  gemm_bt<2><<<dim3(TT / BN, TT / BM, BB), 256, 0, stream>>>(
      qk, qk + BOTC, S, nullptr, TT, TT, BOTC, 2 * BOTC, 2 * BOTC,
      (long)TT * 2 * BOTC, (long)TT * 2 * BOTC, (long)TT * TT, 0.0625f);

  // 4) in-place: S <- 0.7*decay + 0.3*softmax(S)  (prefix-only read)
  softmax_combine<<<dim3(TT, BB), 256, 0, stream>>>(S, decay);

  // 5) out = combined @ hdc  (per batch M=T, N=D, K=T) — 256² 8-phase, spread reads
  gemm256<<<dim3(DD / 256, TT / 256, BB), 512, 0, stream>>>(
      S, hdcT, out, DD, TT, TT, TT,
      (long)TT * TT, (long)DD * TT, (long)TT * DD);
}